// Round 11
// baseline (323.342 us; speedup 1.0000x reference)
//
#include <hip/hip_runtime.h>

typedef short bf16x8 __attribute__((ext_vector_type(8)));
typedef float f32x4 __attribute__((ext_vector_type(4)));

#define DIM 128
#define NLAYER 3
#define NG 64
#define NC 10
#define NXCD 8
#define MAXDEG 64
#define NPASS 8

static __device__ __forceinline__ float b2f(unsigned short u) {
  union { unsigned int i; float f; } x; x.i = ((unsigned int)u) << 16; return x.f;
}
static __device__ __forceinline__ unsigned short f2b(float f) {
  unsigned int x = __float_as_uint(f);
  unsigned int r = (x + 0x7FFFu + ((x >> 16) & 1u)) >> 16;
  return (unsigned short)r;
}

// ---- f32 -> bf16 conversion (h0 mirror) ---------------------------------

__global__ void k_h2b(const float* __restrict__ in, unsigned short* __restrict__ out,
                      int total) {
  int i = blockIdx.x * 256 + threadIdx.x;
  int b = i * 4;
  if (b < total) {
    float4 v = *(const float4*)(in + b);
    ushort4 r;
    r.x = f2b(v.x); r.y = f2b(v.y); r.z = f2b(v.z); r.w = f2b(v.w);
    *(ushort4*)(out + b) = r;
  }
}

// ---- padded adjacency fill, XCD-bucketed, nt streaming loads ------------
// colxp[d][slot] = src for slot < MAXDEG; cur[d] counts true in-degree.
// Bucket slice of cur/colxp (1.6 MB) stays in one XCD's L2; nontemporal
// loads keep the dst/src streams from evicting it.

__global__ __launch_bounds__(256) void k_fillp(const int* __restrict__ src,
    const int* __restrict__ dst, int* __restrict__ cur, int* __restrict__ colxp,
    int e, int n) {
  int bucket = blockIdx.x & (NXCD - 1);
  int chunk = blockIdx.x >> 3, nchunk = gridDim.x >> 3;
  int bs = (n + NXCD - 1) / NXCD;
  int lo = bucket * bs, hi = min(n, lo + bs);
  for (int i = chunk * 256 + threadIdx.x; i < e; i += nchunk * 256) {
    int d = __builtin_nontemporal_load(dst + i);
    if (d >= lo && d < hi) {
      int p = atomicAdd(&cur[d], 1);
      if (p < MAXDEG) colxp[(size_t)d * MAXDEG + p] = __builtin_nontemporal_load(src + i);
    }
  }
}

// wt[l][c][k] = (bf16) w[l][k][c]   (f32 in, bf16 out) — both matrices in one pass
__global__ void k_transw(const float* __restrict__ ws_, const float* __restrict__ wn_,
                         unsigned short* __restrict__ wtS, unsigned short* __restrict__ wtN,
                         int total) {
  int i = blockIdx.x * 256 + threadIdx.x;
  if (i < total) {
    int l = i >> 14, rem = i & 16383, c = rem >> 7, k = rem & 127;
    int sidx = (l << 14) + (k << 7) + c;
    wtS[i] = f2b(ws_[sidx]);
    wtN[i] = f2b(wn_[sidx]);
  }
}

// ---- mean aggregation: register adjacency + 8 src-range passes ----------
// Wave owns node v; lane L holds adjacency slot L. Pass p gathers only src
// rows in [p*step, p*step+step) (1.6 MB -> L2-resident per XCD since all
// co-resident waves walk the same range together). Ballot + uniform ffs/shfl
// extracts <=4 indices per iteration into STATIC regs (no scratch).

__global__ __launch_bounds__(256) void k_agg(const unsigned short* __restrict__ h,
    const int* __restrict__ cur, const int* __restrict__ colxp,
    unsigned short* __restrict__ agg, int n) {
  int wv = threadIdx.x >> 6, lane = threadIdx.x & 63;
  int v = blockIdx.x * 4 + wv;
  if (v >= n) return;
  int deg = cur[v];
  int end = min(deg, MAXDEG);
  int slot = colxp[(size_t)v * MAXDEG + lane];  // garbage if lane >= end (excluded below)
  bool lv = lane < end;
  int off = lane * 2;
  float a0[4], a1[4];
  #pragma unroll
  for (int k = 0; k < 4; ++k) { a0[k] = 0.f; a1[k] = 0.f; }
  int step = (n + NPASS - 1) / NPASS;
  for (int p = 0; p < NPASS; ++p) {
    int lo = p * step;
    int hi = min(n, lo + step);
    unsigned long long m = __ballot(lv && slot >= lo && slot < hi);
    while (m) {
      int s0 = 0, s1 = 0, s2 = 0, s3 = 0, cnt = 0;
      { int b = __ffsll((long long)m) - 1; m &= m - 1; s0 = __shfl(slot, b); cnt = 1; }
      if (m) { int b = __ffsll((long long)m) - 1; m &= m - 1; s1 = __shfl(slot, b); cnt = 2;
        if (m) { int b = __ffsll((long long)m) - 1; m &= m - 1; s2 = __shfl(slot, b); cnt = 3;
          if (m) { int b = __ffsll((long long)m) - 1; m &= m - 1; s3 = __shfl(slot, b); cnt = 4; } } }
      unsigned int p0 = *(const unsigned int*)(h + (size_t)s0 * DIM + off);
      unsigned int p1 = (cnt > 1) ? *(const unsigned int*)(h + (size_t)s1 * DIM + off) : 0u;
      unsigned int p2 = (cnt > 2) ? *(const unsigned int*)(h + (size_t)s2 * DIM + off) : 0u;
      unsigned int p3 = (cnt > 3) ? *(const unsigned int*)(h + (size_t)s3 * DIM + off) : 0u;
      a0[0] += b2f((unsigned short)p0); a1[0] += b2f((unsigned short)(p0 >> 16));
      a0[1] += b2f((unsigned short)p1); a1[1] += b2f((unsigned short)(p1 >> 16));
      a0[2] += b2f((unsigned short)p2); a1[2] += b2f((unsigned short)(p2 >> 16));
      a0[3] += b2f((unsigned short)p3); a1[3] += b2f((unsigned short)(p3 >> 16));
    }
  }
  float s0f = (a0[0] + a0[1]) + (a0[2] + a0[3]);
  float s1f = (a1[0] + a1[1]) + (a1[2] + a1[3]);
  float w = 1.0f / fmaxf((float)deg, 1.0f);
  unsigned int outpk = (unsigned int)f2b(s0f * w) | ((unsigned int)f2b(s1f * w) << 16);
  *(unsigned int*)(agg + (size_t)v * DIM + off) = outpk;
}

// ---- fused dual-GEMM + bias + relu: h_out = relu(h@Ws + agg@Wn + b) -----
// 4 waves/block, wave computes 16 rows x 128 cols, K=128 per operand pair.

__global__ __launch_bounds__(256) void k_gemm(const unsigned short* __restrict__ hin,
    const unsigned short* __restrict__ agg, const unsigned short* __restrict__ wtS,
    const unsigned short* __restrict__ wtN, const float* __restrict__ bias,
    unsigned short* __restrict__ hout, int n) {
  int lane = threadIdx.x & 63, wv = threadIdx.x >> 6;
  int row0 = blockIdx.x * 64 + wv * 16;
  int r = lane & 15, q = lane >> 4;
  int arow = row0 + r; if (arow > n - 1) arow = n - 1;
  const unsigned short* hp = hin + (size_t)arow * DIM + q * 8;
  const unsigned short* gp = agg + (size_t)arow * DIM + q * 8;
  bf16x8 ah[4], ag[4];
  #pragma unroll
  for (int kf = 0; kf < 4; ++kf) {
    ah[kf] = *(const bf16x8*)(hp + kf * 32);
    ag[kf] = *(const bf16x8*)(gp + kf * 32);
  }
  #pragma unroll
  for (int cf = 0; cf < 8; ++cf) {
    f32x4 acc = {0.f, 0.f, 0.f, 0.f};
    const unsigned short* wsp = wtS + (size_t)(cf * 16 + r) * DIM + q * 8;
    const unsigned short* wnp = wtN + (size_t)(cf * 16 + r) * DIM + q * 8;
    #pragma unroll
    for (int kf = 0; kf < 4; ++kf) {
      bf16x8 bs = *(const bf16x8*)(wsp + kf * 32);
      acc = __builtin_amdgcn_mfma_f32_16x16x32_bf16(ah[kf], bs, acc, 0, 0, 0);
    }
    #pragma unroll
    for (int kf = 0; kf < 4; ++kf) {
      bf16x8 bn = *(const bf16x8*)(wnp + kf * 32);
      acc = __builtin_amdgcn_mfma_f32_16x16x32_bf16(ag[kf], bn, acc, 0, 0, 0);
    }
    int col = cf * 16 + r;
    float bval = bias[col];
    #pragma unroll
    for (int j = 0; j < 4; ++j) {
      int orow = row0 + q * 4 + j;
      if (orow < n) {
        float vv = acc[j] + bval;
        vv = vv > 0.f ? vv : 0.f;
        hout[(size_t)orow * DIM + col] = f2b(vv);
      }
    }
  }
}

// ---- readout: sorted graph_id -> run-length register accumulation -------

__global__ __launch_bounds__(256) void k_readout(const unsigned short* __restrict__ h,
    const int* __restrict__ gid, float* __restrict__ hg, int n) {
  int c = threadIdx.x & 127, half = threadIdx.x >> 7;
  int per = (n + gridDim.x - 1) / gridDim.x;
  int beg = blockIdx.x * per;
  int end = beg + per; if (end > n) end = n;
  int curg = -1;
  float acc = 0.f;
  for (int v = beg + half; v < end; v += 2) {
    int g = gid[v];
    if (g != curg) {
      if (curg >= 0) atomicAdd(&hg[curg * DIM + c], acc);
      curg = g; acc = 0.f;
    }
    acc += b2f(h[(size_t)v * DIM + c]);
  }
  if (curg >= 0) atomicAdd(&hg[curg * DIM + c], acc);
}

// ---- head: counts via binary search on sorted gid, then [G,D]@[D,C] -----

__global__ void k_head(const float* __restrict__ hg, const int* __restrict__ gid, int n,
    const float* __restrict__ wcls, const float* __restrict__ bcls,
    float* __restrict__ out) {
  __shared__ float sinv[NG];
  int t = threadIdx.x;
  if (t < NG) {
    int lo = 0, hi = n;
    while (lo < hi) { int mid = (lo + hi) >> 1; if (gid[mid] < t) lo = mid + 1; else hi = mid; }
    int lo2 = lo, hi2 = n;
    while (lo2 < hi2) { int mid = (lo2 + hi2) >> 1; if (gid[mid] < t + 1) lo2 = mid + 1; else hi2 = mid; }
    int cntg = lo2 - lo;
    sinv[t] = 1.0f / fmaxf((float)cntg, 1.0f);
  }
  __syncthreads();
  if (t >= NG * NC) return;
  int g = t / NC, c = t % NC;
  float s = 0.f;
  for (int k = 0; k < DIM; ++k) s += hg[g * DIM + k] * wcls[k * NC + c];
  out[t] = s * sinv[g] + bcls[c];
}

// ---- launch -------------------------------------------------------------

extern "C" void kernel_launch(void* const* d_in, const int* in_sizes, int n_in,
                              void* d_out, int out_size, void* d_ws, size_t ws_size,
                              hipStream_t stream) {
  const float* h0   = (const float*)d_in[0];
  const int* src    = (const int*)d_in[1];
  const int* dst    = (const int*)d_in[2];
  const int* gid    = (const int*)d_in[3];
  const float* wself  = (const float*)d_in[5];
  const float* wneigh = (const float*)d_in[6];
  const float* bias   = (const float*)d_in[7];
  const float* wcls   = (const float*)d_in[8];
  const float* bcls   = (const float*)d_in[9];
  int n = in_sizes[0] / DIM;
  int e = in_sizes[1];
  (void)n_in; (void)out_size; (void)ws_size;

  char* ws = (char*)d_ws;
  size_t o = 0;
  auto alloc = [&](size_t bytes) {
    char* p = ws + o;
    o = (o + bytes + 255) & ~(size_t)255;
    return p;
  };
  unsigned short* h_a   = (unsigned short*)alloc((size_t)n * DIM * 2);
  unsigned short* h_b   = (unsigned short*)alloc((size_t)n * DIM * 2);
  unsigned short* aggb  = (unsigned short*)alloc((size_t)n * DIM * 2);
  unsigned short* wtS   = (unsigned short*)alloc((size_t)NLAYER * DIM * DIM * 2);
  unsigned short* wtN   = (unsigned short*)alloc((size_t)NLAYER * DIM * DIM * 2);
  int*   cur   = (int*)alloc((size_t)n * 4);
  int*   colxp = (int*)alloc((size_t)n * MAXDEG * 4);
  float* hg    = (float*)alloc((size_t)NG * DIM * 4);

  hipMemsetAsync(cur, 0, (size_t)n * 4, stream);
  hipMemsetAsync(hg, 0, (size_t)NG * DIM * 4, stream);

  k_h2b<<<((n * DIM / 4) + 255) / 256, 256, 0, stream>>>(h0, h_a, n * DIM);
  k_fillp<<<2048, 256, 0, stream>>>(src, dst, cur, colxp, e, n);
  k_transw<<<(NLAYER * DIM * DIM + 255) / 256, 256, 0, stream>>>(wself, wneigh, wtS, wtN,
                                                                 NLAYER * DIM * DIM);

  const unsigned short* hin = h_a;
  unsigned short* hout = h_b;
  for (int l = 0; l < NLAYER; ++l) {
    k_agg<<<(n + 3) / 4, 256, 0, stream>>>(hin, cur, colxp, aggb, n);
    k_gemm<<<(n + 63) / 64, 256, 0, stream>>>(hin, aggb, wtS + l * DIM * DIM,
                                              wtN + l * DIM * DIM, bias + l * DIM,
                                              hout, n);
    const unsigned short* t = hin;
    hin = hout;
    hout = (unsigned short*)t;
  }
  k_readout<<<512, 256, 0, stream>>>(hin, gid, hg, n);
  k_head<<<1, 640, 0, stream>>>(hg, gid, n, wcls, bcls, (float*)d_out);
}